// Round 5
// baseline (5966.739 us; speedup 1.0000x reference)
//
#include <hip/hip_runtime.h>
#include <hip/hip_bf16.h>
#include <stdint.h>

#define TT 4096
#define EE 256
#define LL 20
#define STARTT 18
#define STOPP 19
#define NEGV -10000.0f
#define NCH 256   // TT/16

typedef short v8s __attribute__((ext_vector_type(8)));
typedef float v4f __attribute__((ext_vector_type(4)));

// ---------- helpers ----------
__device__ inline float bf2f(unsigned short u){
  unsigned int x = ((unsigned int)u) << 16;
  return __builtin_bit_cast(float, x);
}
__device__ inline unsigned short f2bf(float f){
  unsigned int x = __builtin_bit_cast(unsigned int, f);
  unsigned int r = (x + 0x7FFFu + ((x >> 16) & 1u)) >> 16;
  return (unsigned short)r;
}

#if __has_builtin(__builtin_amdgcn_sdot4)
#define SDOT4(a,b,c) __builtin_amdgcn_sdot4((int)(a),(int)(b),(c),false)
#else
__device__ inline int sdot4_sw(int a, int b, int c){
  return c + (int)(char)(a)        * (int)(char)(b)
           + (int)(char)(a >> 8)   * (int)(char)(b >> 8)
           + (int)(char)(a >> 16)  * (int)(char)(b >> 16)
           + (int)(char)(a >> 24)  * (int)(char)(b >> 24);
}
#define SDOT4(a,b,c) sdot4_sw((int)(a),(int)(b),(c))
#endif

// lgkm-only barrier: syncs LDS without draining outstanding global (vmcnt) prefetch
#define BARRIER_LDS() asm volatile("s_waitcnt lgkmcnt(0)\ns_barrier" ::: "memory")

// ---------- workspace layout (bytes) ----------
constexpr size_t OFF_U    = 0;                              // bf16 [2][T][256][4] (elem-major, 4 gates packed)
constexpr size_t SZ_U     = 2ull*TT*1024*2;
constexpr size_t OFF_X    = OFF_U + SZ_U;                   // bf16 [T][E]
constexpr size_t SZ_X     = (size_t)TT*EE*2;
constexpr size_t OFF_WIH  = OFF_X + SZ_X;                   // bf16 [2048][256]
constexpr size_t SZ_WIH   = 2048ull*256*2;
constexpr size_t OFF_BIAS = OFF_WIH + SZ_WIH;               // f32 [2048]
constexpr size_t SZ_BIAS  = 2048ull*4;
constexpr size_t OFF_WQ   = OFF_BIAS + SZ_BIAS;             // uint4 [2][64][256] (i8 packed, lane-local layout)
constexpr size_t SZ_WQ    = 2ull*64*256*16;
constexpr size_t OFF_FS   = OFF_WQ + SZ_WQ;                 // float4 [2][256] (per-elem 4 gate scales)
constexpr size_t SZ_FS    = 2ull*256*16;
constexpr size_t OFF_WOP  = OFF_FS + SZ_FS;                 // bf16 [32][512]
constexpr size_t SZ_WOP   = 32ull*512*2;
constexpr size_t OFF_HOUT = OFF_WOP + SZ_WOP;               // bf16 [T][512]
constexpr size_t SZ_HOUT  = (size_t)TT*512*2;
constexpr size_t OFF_FE   = OFF_HOUT + SZ_HOUT;             // f32 [T][20]
constexpr size_t SZ_FE    = (size_t)TT*LL*4;
constexpr size_t OFF_P    = OFF_FE + SZ_FE;                 // f32 [256][20][20]
constexpr size_t SZ_P     = 256ull*400*4;
constexpr size_t OFF_BAL  = OFF_P + SZ_P;                   // f32 [257][20]
constexpr size_t SZ_BAL   = 20736;
constexpr size_t OFF_BP   = OFF_BAL + SZ_BAL;               // u8 [T][20]
constexpr size_t SZ_BP    = (size_t)TT*LL;
constexpr size_t OFF_M    = OFF_BP + SZ_BP;                 // u8 [256][20]
constexpr size_t SZ_M     = 256ull*LL;
constexpr size_t OFF_EG   = OFF_M + SZ_M + 64;              // i32 [256]

// ---------- prep kernels ----------

__global__ void k_gather(const int* __restrict__ x, const float* __restrict__ emb,
                         unsigned short* __restrict__ X){
  int t = blockIdx.x;
  int xt = x[t];
  const float4* src = (const float4*)(emb + (size_t)xt * EE);
  float4 v = src[threadIdx.x];
  ushort4 o;
  o.x = f2bf(v.x); o.y = f2bf(v.y); o.z = f2bf(v.z); o.w = f2bf(v.w);
  ((ushort4*)(X + (size_t)t * EE))[threadIdx.x] = o;
}

__global__ void k_wih(const float* __restrict__ wf, const float* __restrict__ wb,
                      unsigned short* __restrict__ WIH){
  int gid = blockIdx.x * 256 + threadIdx.x;   // 65536
  int row = gid >> 5, c8 = gid & 31;
  const float* src = (row < 1024 ? wf + (size_t)row * EE : wb + (size_t)(row - 1024) * EE) + c8 * 8;
  unsigned short* dst = WIH + (size_t)row * 256 + c8 * 8;
#pragma unroll
  for (int i = 0; i < 8; i++) dst[i] = f2bf(src[i]);
}

__global__ void k_bias(const float* bf, const float* hf, const float* bb, const float* hb,
                       float* __restrict__ bias){
  int i = blockIdx.x * 256 + threadIdx.x;     // 2048
  int r = i & 1023;
  bias[i] = (i < 1024) ? (bf[r] + hf[r]) : (bb[r] + hb[r]);
}

// w_out -> bf16, padded to 32 rows
__global__ void k_wout(const float* __restrict__ wout, unsigned short* __restrict__ WOP){
  int gid = blockIdx.x * 256 + threadIdx.x;   // 16384 = 32*512
  int row = gid >> 9, k = gid & 511;
  WOP[gid] = (row < LL) ? f2bf(wout[row * 512 + k]) : 0;
}

// quantize W_hh rows to int8 with per-row scale, LANE-LOCAL layout:
// core lane J (0..255) owns all 4 gate rows of element J, full K=256.
// quad index q = g*16 + kq (kq = 16-byte chunk of the row).
// WQ[((d*64 + q)*256 + J)*4 + comp]. FS float4[d*256+J] = per-gate scales.
__global__ void k_whh7(const float* __restrict__ whf, const float* __restrict__ whb,
                       unsigned int* __restrict__ WQ, float* __restrict__ FS){
  int row = blockIdx.x;       // 0..2047
  int d = row >> 10, R = row & 1023;
  int g = R >> 8, J = R & 255;
  const float* W = (d ? whb : whf) + (size_t)R * 256;
  int t = threadIdx.x;        // 0..63 ; covers cols 4t..4t+3
  float4 v = ((const float4*)W)[t];
  float m = fmaxf(fmaxf(fabsf(v.x), fabsf(v.y)), fmaxf(fabsf(v.z), fabsf(v.w)));
#pragma unroll
  for (int o = 32; o >= 1; o >>= 1) m = fmaxf(m, __shfl_down(m, o));
  m = __shfl(m, 0);
  float sc = (m > 0.f) ? (m / 127.f) : 1.f;
  float inv = 1.f / sc;
  int a = (int)rintf(v.x * inv), b = (int)rintf(v.y * inv);
  int c = (int)rintf(v.z * inv), e4 = (int)rintf(v.w * inv);
  unsigned int pack = ((unsigned)a & 255u) | (((unsigned)b & 255u) << 8)
                    | (((unsigned)c & 255u) << 16) | (((unsigned)e4 & 255u) << 24);
  int kq = t >> 2, comp = t & 3;
  int q = g * 16 + kq;
  WQ[(((size_t)(d * 64 + q)) * 256 + J) * 4 + comp] = pack;
  if (t == 0) FS[((size_t)d * 256 + J) * 4 + g] = sc;
}

// U[d][t][J][g] = bf16( X[t]·W_ih row (g*256+J) + bias )  via 16x16x32 bf16 MFMA
__global__ void k_gemm_u(const unsigned short* __restrict__ X,
                         const unsigned short* __restrict__ WIH,
                         const float* __restrict__ bias,
                         unsigned short* __restrict__ U){
  int wave = threadIdx.x >> 6, l = threadIdx.x & 63;
  int tile = blockIdx.x * 4 + wave;           // 0..32767
  int mt = tile & 255, nt = tile >> 8;        // 256 x 128 tiles
  int lm = l & 15, lq = l >> 4;
  const unsigned short* Arow = X   + (size_t)(mt * 16 + lm) * 256 + lq * 8;
  const unsigned short* Brow = WIH + (size_t)(nt * 16 + lm) * 256 + lq * 8;
  v4f acc = {0.f, 0.f, 0.f, 0.f};
#pragma unroll
  for (int kb = 0; kb < 8; kb++){
    v8s a = *(const v8s*)(Arow + kb * 32);
    v8s b = *(const v8s*)(Brow + kb * 32);
    acc = __builtin_amdgcn_mfma_f32_16x16x32_bf16(a, b, acc, 0, 0, 0);
  }
  int n = nt * 16 + lm;                       // 0..2047 gate-row
  int dd = n >> 10, r = n & 1023;
  int g = r >> 8, J = r & 255;
  float bi = bias[n];
#pragma unroll
  for (int r4 = 0; r4 < 4; r4++){
    int t = mt * 16 + lq * 4 + r4;
    U[(((size_t)(dd * TT + t)) * 256 + J) * 4 + g] = f2bf(acc[r4] + bi);
  }
}

// ---------- the recurrent core ----------
// grid=2 (one CU per direction), block=256 (4 waves, 1/SIMD, 512-reg unified budget).
// LANE-LOCAL mapping: lane J owns ALL 4 gate rows of element J, full K=256:
// 256 weight u32 pinned in AGPRs ("a" constraint; v_dot4 reads AGPRs natively on
// gfx950 unified RF — R2 instr-count evidence). The step has ZERO cross-lane ops:
// no shfl, no gate exchange, no divergence. LDS: 16 broadcast ds_read_b128 per
// wave (h vector) + 1-byte h write; one lgkm barrier per step across 4 waves.
// This minimizes the per-step critical path (barrier makes waves stall in
// lockstep, so latency-hiding via extra waves does not work here — R0-R2 data).

#define Q64(M) M(0) M(1) M(2) M(3) M(4) M(5) M(6) M(7) \
               M(8) M(9) M(10) M(11) M(12) M(13) M(14) M(15) \
               M(16) M(17) M(18) M(19) M(20) M(21) M(22) M(23) \
               M(24) M(25) M(26) M(27) M(28) M(29) M(30) M(31) \
               M(32) M(33) M(34) M(35) M(36) M(37) M(38) M(39) \
               M(40) M(41) M(42) M(43) M(44) M(45) M(46) M(47) \
               M(48) M(49) M(50) M(51) M(52) M(53) M(54) M(55) \
               M(56) M(57) M(58) M(59) M(60) M(61) M(62) M(63)

#define DECLW(q) unsigned wx_##q, wy_##q, wz_##q, ww_##q;
#define LOADW(q) { uint4 _tw = WQ4[wb + (size_t)(q) * 256]; \
                   wx_##q = _tw.x; wy_##q = _tw.y; wz_##q = _tw.z; ww_##q = _tw.w; }
#define PINW(q) asm volatile("" : "+a"(wx_##q), "+a"(wy_##q), "+a"(wz_##q), "+a"(ww_##q));
#define DOT(q, A) { uint4 _h = hq[(q) & 15]; \
  A = SDOT4(wx_##q, _h.x, A); A = SDOT4(wy_##q, _h.y, A); \
  A = SDOT4(wz_##q, _h.z, A); A = SDOT4(ww_##q, _h.w, A); }

__global__ void __launch_bounds__(256)
__attribute__((amdgpu_waves_per_eu(1, 4)))
k_lstm11(
    const unsigned short* __restrict__ U, const uint4* __restrict__ WQ4,
    const float4* __restrict__ FS4, const float* __restrict__ h0,
    const float* __restrict__ c0, unsigned short* __restrict__ hout){
  int d = blockIdx.x;
  int J = threadIdx.x;          // hidden element 0..255, fully lane-local

  __shared__ __align__(16) unsigned char hb[2][256];

  Q64(DECLW)
  {
    size_t wb = (size_t)d * 64 * 256 + J;     // uint4 units; quad q at wb + q*256
    Q64(LOADW)
  }
  Q64(PINW)

  float4 fsv = FS4[(size_t)d * 256 + J];      // per-gate scales (i,f,g,o)

  float cst = c0[d * 256 + J];
  {
    float hini = h0[d * 256 + J];
    hini = fminf(fmaxf(hini, -8.f), 8.f);
    hb[0][J] = (unsigned char)(char)(int)rintf(hini * (127.f / 8.f));
  }

  const unsigned short* Up0 = U + (size_t)d * TT * 1024 + (size_t)J * 4;
  int stp = d ? -1 : 1;
  int tA = d ? TT - 1 : 0;
  uint2 u_c = *(const uint2*)(Up0 + (size_t)tA * 1024);
  uint2 u_n = *(const uint2*)(Up0 + (size_t)(tA + stp) * 1024);

  unsigned short* hp = hout + (size_t)tA * 512 + d * 256 + J;

  __syncthreads();

  for (int s = 0; s < TT; s++){
    int par = s & 1;
    int tt = d ? (TT - 1 - s) : s;
    const uint4* hq = (const uint4*)(&hb[par][0]);   // uniform → broadcast reads

    int ai0 = 0, ai1 = 0, af0 = 0, af1 = 0;
    int ag0 = 0, ag1 = 0, ao0 = 0, ao1 = 0;
    // gate i: quads 0..15
    DOT(0,  ai0) DOT(1,  ai1) DOT(2,  ai0) DOT(3,  ai1)
    DOT(4,  ai0) DOT(5,  ai1) DOT(6,  ai0) DOT(7,  ai1)
    DOT(8,  ai0) DOT(9,  ai1) DOT(10, ai0) DOT(11, ai1)
    DOT(12, ai0) DOT(13, ai1) DOT(14, ai0) DOT(15, ai1)
    // gate f: quads 16..31
    DOT(16, af0) DOT(17, af1) DOT(18, af0) DOT(19, af1)
    DOT(20, af0) DOT(21, af1) DOT(22, af0) DOT(23, af1)
    DOT(24, af0) DOT(25, af1) DOT(26, af0) DOT(27, af1)
    DOT(28, af0) DOT(29, af1) DOT(30, af0) DOT(31, af1)
    // gate g: quads 32..47
    DOT(32, ag0) DOT(33, ag1) DOT(34, ag0) DOT(35, ag1)
    DOT(36, ag0) DOT(37, ag1) DOT(38, ag0) DOT(39, ag1)
    DOT(40, ag0) DOT(41, ag1) DOT(42, ag0) DOT(43, ag1)
    DOT(44, ag0) DOT(45, ag1) DOT(46, ag0) DOT(47, ag1)
    // gate o: quads 48..63
    DOT(48, ao0) DOT(49, ao1) DOT(50, ao0) DOT(51, ao1)
    DOT(52, ao0) DOT(53, ao1) DOT(54, ao0) DOT(55, ao1)
    DOT(56, ao0) DOT(57, ao1) DOT(58, ao0) DOT(59, ao1)
    DOT(60, ao0) DOT(61, ao1) DOT(62, ao0) DOT(63, ao1)

    int aI = ai0 + ai1, aF = af0 + af1, aG = ag0 + ag1, aO = ao0 + ao1;

    float m1 = (s == 0) ? (8.f / 127.f) : (1.f / 127.f);
    float u_i = bf2f((unsigned short)(u_c.x & 0xffffu));
    float u_f = bf2f((unsigned short)(u_c.x >> 16));
    float u_g = bf2f((unsigned short)(u_c.y & 0xffffu));
    float u_o = bf2f((unsigned short)(u_c.y >> 16));
    float zi = u_i + (float)aI * (fsv.x * m1);
    float zf = u_f + (float)aF * (fsv.y * m1);
    float zg = u_g + (float)aG * (fsv.z * m1);
    float zo = u_o + (float)aO * (fsv.w * m1);

    // rotate u prefetch (2 steps ahead; clamped always-load)
    u_c = u_n;
    {
      int t2 = tt + 2 * stp;
      t2 = t2 < 0 ? 0 : (t2 > TT - 1 ? TT - 1 : t2);
      u_n = *(const uint2*)(Up0 + (size_t)t2 * 1024);
    }

    // activations (all lanes, all 4 gates local)
    float za = fminf(fmaxf(zi, -87.f), 87.f);
    float ea = __expf(-za);
    float gi = __builtin_amdgcn_rcpf(1.f + ea);
    float zb = fminf(fmaxf(zf, -87.f), 87.f);
    float eb = __expf(-zb);
    float gf = __builtin_amdgcn_rcpf(1.f + eb);
    float zc = fminf(fmaxf(zg, -20.f), 20.f);
    float ec = __expf(-2.f * zc);
    float gg = (1.f - ec) * __builtin_amdgcn_rcpf(1.f + ec);
    float zd = fminf(fmaxf(zo, -87.f), 87.f);
    float ed = __expf(-zd);
    float go = __builtin_amdgcn_rcpf(1.f + ed);

    cst = fmaf(gf, cst, gi * gg);
    float cc = fminf(fmaxf(cst, -20.f), 20.f);
    float e2 = __expf(-2.f * cc);
    float th = (1.f - e2) * __builtin_amdgcn_rcpf(1.f + e2);
    float h = go * th;

    int qv = (int)rintf(fminf(fmaxf(h, -1.f), 1.f) * 127.f);
    hb[par ^ 1][J] = (unsigned char)(char)qv;   // 64 B per wave, byte writes
    *hp = f2bf(h);                              // 128 B contiguous per wave
    hp += stp * 512;

    BARRIER_LDS();
  }
}

// feats via MFMA: FE[t][j] = HOUT[t]·WOP[j] + bout[j], WOP padded to 32 rows
__global__ void k_feats2(const unsigned short* __restrict__ HOUT,
                         const unsigned short* __restrict__ WOP,
                         const float* __restrict__ bout,
                         float* __restrict__ feats){
  int wave = threadIdx.x >> 6, l = threadIdx.x & 63;
  int tile = blockIdx.x * 4 + wave;           // 0..511
  int mt = tile & 255, nt = tile >> 8;        // 256 M-tiles x 2 N-tiles
  int lm = l & 15, lq = l >> 4;
  const unsigned short* Arow = HOUT + (size_t)(mt * 16 + lm) * 512 + lq * 8;
  const unsigned short* Brow = WOP  + (size_t)(nt * 16 + lm) * 512 + lq * 8;
  v4f acc = {0.f, 0.f, 0.f, 0.f};
#pragma unroll
  for (int kb = 0; kb < 16; kb++){
    v8s a = *(const v8s*)(Arow + kb * 32);
    v8s b = *(const v8s*)(Brow + kb * 32);
    acc = __builtin_amdgcn_mfma_f32_16x16x32_bf16(a, b, acc, 0, 0, 0);
  }
  int n = nt * 16 + lm;
  if (n < LL){
    float bi = bout[n];
#pragma unroll
    for (int r4 = 0; r4 < 4; r4++){
      int t = mt * 16 + lq * 4 + r4;
      feats[t * LL + n] = acc[r4] + bi;
    }
  }
}

// V1: per-chunk max-plus matrix product
__global__ void k_vchunk(const float* __restrict__ feats, const float* __restrict__ trans,
                         float* __restrict__ P){
  int c = blockIdx.x, j = threadIdx.x;
  __shared__ float Ps[2][LL][LL];
  bool act = j < LL;
  float trow[LL];
  if (act){
#pragma unroll
    for (int i = 0; i < LL; i++) trow[i] = trans[j * LL + i];
    for (int i = 0; i < LL; i++) Ps[0][i][j] = (i == j) ? 0.f : -1e30f;
  }
  __syncthreads();
  for (int s = 0; s < 16; s++){
    int t = c * 16 + s;
    int pb = s & 1;
    if (act){
      float fj = feats[t * LL + j];
      for (int i = 0; i < LL; i++){
        float m = Ps[pb][i][0] + trow[0];
#pragma unroll
        for (int mm = 1; mm < LL; mm++) m = fmaxf(m, Ps[pb][i][mm] + trow[mm]);
        Ps[pb ^ 1][i][j] = m + fj;
      }
    }
    __syncthreads();
  }
  if (act)
    for (int i = 0; i < LL; i++) P[((size_t)c * LL + i) * LL + j] = Ps[0][i][j];
}

// V2: sequential boundary-alpha scan (prefetch-pipelined)
__global__ void k_vscan(const float* __restrict__ P, float* __restrict__ bal){
  int tid = threadIdx.x;
  bool act = tid < LL;
  __shared__ float al[LL];
  __shared__ float Pl[400];
  if (act){
    float a = (tid == STARTT) ? 0.f : NEGV;
    al[tid] = a;
    bal[tid] = a;
  }
  for (int k = tid; k < 400; k += 64) Pl[k] = P[k];
  __syncthreads();
  for (int c = 0; c < NCH; c++){
    float p0 = 0.f, p1 = 0.f, p2 = 0.f, p3 = 0.f, p4 = 0.f, p5 = 0.f, p6 = 0.f;
    if (c + 1 < NCH){
      const float* Pn = P + (size_t)(c + 1) * 400;
      p0 = Pn[tid];        p1 = Pn[tid + 64];  p2 = Pn[tid + 128];
      p3 = Pn[tid + 192];  p4 = Pn[tid + 256]; p5 = Pn[tid + 320];
      if (tid + 384 < 400) p6 = Pn[tid + 384];
    }
    float m = -1e30f;
    if (act){
      m = al[0] + Pl[tid];
#pragma unroll
      for (int i = 1; i < LL; i++) m = fmaxf(m, al[i] + Pl[i * LL + tid]);
    }
    __syncthreads();
    if (act){
      al[tid] = m;
      bal[(c + 1) * LL + tid] = m;
    }
    if (c + 1 < NCH){
      Pl[tid] = p0;        Pl[tid + 64] = p1;  Pl[tid + 128] = p2;
      Pl[tid + 192] = p3;  Pl[tid + 256] = p4; Pl[tid + 320] = p5;
      if (tid + 384 < 400) Pl[tid + 384] = p6;
    }
    __syncthreads();
  }
}

// V3: per-chunk backpointers + chunk backtrace map
__global__ void k_vbp(const float* __restrict__ feats, const float* __restrict__ trans,
                      const float* __restrict__ bal, unsigned char* __restrict__ bp,
                      unsigned char* __restrict__ M){
  int c = blockIdx.x, j = threadIdx.x;
  bool act = j < LL;
  __shared__ float al[2][LL];
  __shared__ unsigned char bpl[16][LL];
  float trow[LL];
  if (act){
#pragma unroll
    for (int i = 0; i < LL; i++) trow[i] = trans[j * LL + i];
    al[0][j] = bal[c * LL + j];
  }
  __syncthreads();
  for (int s = 0; s < 16; s++){
    int t = c * 16 + s;
    int pb = s & 1;
    if (act){
      float m = al[pb][0] + trow[0];
      int arg = 0;
#pragma unroll
      for (int i = 1; i < LL; i++){
        float v = al[pb][i] + trow[i];
        if (v > m){ m = v; arg = i; }
      }
      bpl[s][j] = (unsigned char)arg;
      bp[(size_t)t * LL + j] = (unsigned char)arg;
      al[pb ^ 1][j] = m + feats[t * LL + j];
    }
    __syncthreads();
  }
  if (act){
    int tag = j;
    for (int s = 15; s >= 0; s--) tag = bpl[s][tag];
    M[c * LL + j] = (unsigned char)tag;
  }
}

// V4: final score + chunk-boundary tag chase
__global__ void k_vtag(const float* __restrict__ bal, const float* __restrict__ trans,
                       const unsigned char* __restrict__ M, int* __restrict__ Eg,
                       float* __restrict__ out){
  int tid = threadIdx.x;
  __shared__ unsigned char Ml[NCH * LL];
  __shared__ float fin[LL];
  for (int k = tid; k < NCH * LL; k += 64) Ml[k] = M[k];
  if (tid < LL) fin[tid] = bal[NCH * LL + tid] + trans[STOPP * LL + tid];
  __syncthreads();
  if (tid == 0){
    float m = fin[0]; int arg = 0;
    for (int i = 1; i < LL; i++) if (fin[i] > m){ m = fin[i]; arg = i; }
    out[0] = m;
    int tag = arg;
    Eg[NCH - 1] = tag;
    for (int c = NCH - 1; c >= 1; c--){
      tag = Ml[c * LL + tag];
      Eg[c - 1] = tag;
    }
  }
}

// V5: parallel path emission
__global__ void k_vemit(const int* __restrict__ Eg, const unsigned char* __restrict__ bp,
                        float* __restrict__ out){
  int c = threadIdx.x;
  int tag = Eg[c];
  out[1 + c * 16 + 15] = (float)tag;
  for (int s = 15; s >= 1; s--){
    tag = bp[(size_t)(c * 16 + s) * LL + tag];
    out[1 + c * 16 + s - 1] = (float)tag;
  }
}

// ---------- launcher ----------
extern "C" void kernel_launch(void* const* d_in, const int* in_sizes, int n_in,
                              void* d_out, int out_size, void* d_ws, size_t ws_size,
                              hipStream_t stream){
  (void)in_sizes; (void)n_in; (void)out_size; (void)ws_size;
  const int*   x     = (const int*)d_in[0];
  const float* emb   = (const float*)d_in[1];
  const float* wihf  = (const float*)d_in[2];
  const float* whhf  = (const float*)d_in[3];
  const float* bihf  = (const float*)d_in[4];
  const float* bhhf  = (const float*)d_in[5];
  const float* wihb  = (const float*)d_in[6];
  const float* whhb  = (const float*)d_in[7];
  const float* bihb  = (const float*)d_in[8];
  const float* bhhb  = (const float*)d_in[9];
  const float* wout  = (const float*)d_in[10];
  const float* bout  = (const float*)d_in[11];
  const float* trans = (const float*)d_in[12];
  const float* h0    = (const float*)d_in[13];
  const float* c0    = (const float*)d_in[14];
  float* out = (float*)d_out;
  char* ws = (char*)d_ws;

  unsigned short* U    = (unsigned short*)(ws + OFF_U);
  unsigned short* X    = (unsigned short*)(ws + OFF_X);
  unsigned short* WIH  = (unsigned short*)(ws + OFF_WIH);
  float*          BIAS = (float*)(ws + OFF_BIAS);
  unsigned int*   WQ   = (unsigned int*)(ws + OFF_WQ);
  float*          FS   = (float*)(ws + OFF_FS);
  unsigned short* WOP  = (unsigned short*)(ws + OFF_WOP);
  unsigned short* HOUT = (unsigned short*)(ws + OFF_HOUT);
  float*          FE   = (float*)(ws + OFF_FE);
  float*          P    = (float*)(ws + OFF_P);
  float*          BAL  = (float*)(ws + OFF_BAL);
  unsigned char*  BP   = (unsigned char*)(ws + OFF_BP);
  unsigned char*  M    = (unsigned char*)(ws + OFF_M);
  int*            EG   = (int*)(ws + OFF_EG);

  k_gather<<<TT, 64, 0, stream>>>(x, emb, X);
  k_wih<<<256, 256, 0, stream>>>(wihf, wihb, WIH);
  k_bias<<<8, 256, 0, stream>>>(bihf, bhhf, bihb, bhhb, BIAS);
  k_wout<<<64, 256, 0, stream>>>(wout, WOP);
  k_whh7<<<2048, 64, 0, stream>>>(whhf, whhb, WQ, FS);
  k_gemm_u<<<8192, 256, 0, stream>>>(X, WIH, BIAS, U);
  k_lstm11<<<2, 256, 0, stream>>>(U, (const uint4*)WQ, (const float4*)FS, h0, c0, HOUT);
  k_feats2<<<128, 256, 0, stream>>>(HOUT, WOP, bout, FE);
  k_vchunk<<<NCH, 64, 0, stream>>>(FE, trans, P);
  k_vscan<<<1, 64, 0, stream>>>(P, BAL);
  k_vbp<<<NCH, 64, 0, stream>>>(FE, trans, BAL, BP, M);
  k_vtag<<<1, 64, 0, stream>>>(BAL, trans, M, EG, out);
  k_vemit<<<1, 256, 0, stream>>>(EG, BP, out);
}

// Round 6
// 3199.267 us; speedup vs baseline: 1.8650x; 1.8650x over previous
//
#include <hip/hip_runtime.h>
#include <hip/hip_bf16.h>
#include <stdint.h>

#define TT 4096
#define EE 256
#define LL 20
#define STARTT 18
#define STOPP 19
#define NEGV -10000.0f
#define NCH 256   // TT/16

typedef short v8s __attribute__((ext_vector_type(8)));
typedef float v4f __attribute__((ext_vector_type(4)));
typedef int   v4i __attribute__((ext_vector_type(4)));

// ---------- helpers ----------
__device__ inline float bf2f(unsigned short u){
  unsigned int x = ((unsigned int)u) << 16;
  return __builtin_bit_cast(float, x);
}
__device__ inline unsigned short f2bf(float f){
  unsigned int x = __builtin_bit_cast(unsigned int, f);
  unsigned int r = (x + 0x7FFFu + ((x >> 16) & 1u)) >> 16;
  return (unsigned short)r;
}

// lgkm-only barrier: syncs LDS without draining outstanding global (vmcnt) prefetch
#define BARRIER_LDS() asm volatile("s_waitcnt lgkmcnt(0)\ns_barrier" ::: "memory")

// ---------- workspace layout (bytes) ----------
constexpr size_t OFF_U    = 0;                              // bf16 [2][T][256][4] (elem-major, 4 gates packed)
constexpr size_t SZ_U     = 2ull*TT*1024*2;
constexpr size_t OFF_X    = OFF_U + SZ_U;                   // bf16 [T][E]
constexpr size_t SZ_X     = (size_t)TT*EE*2;
constexpr size_t OFF_WIH  = OFF_X + SZ_X;                   // bf16 [2048][256]
constexpr size_t SZ_WIH   = 2048ull*256*2;
constexpr size_t OFF_BIAS = OFF_WIH + SZ_WIH;               // f32 [2048]
constexpr size_t SZ_BIAS  = 2048ull*4;
constexpr size_t OFF_WQ   = OFF_BIAS + SZ_BIAS;             // v4i [2][8w][8nt][4kt][64lane] (i8 MFMA B-fragments)
constexpr size_t SZ_WQ    = 2ull*8*8*4*64*16;
constexpr size_t OFF_FS   = OFF_WQ + SZ_WQ;                 // float4 [2][256] (per-elem 4 gate scales)
constexpr size_t SZ_FS    = 2ull*256*16;
constexpr size_t OFF_WOP  = OFF_FS + SZ_FS;                 // bf16 [32][512]
constexpr size_t SZ_WOP   = 32ull*512*2;
constexpr size_t OFF_HOUT = OFF_WOP + SZ_WOP;               // bf16 [T][512]
constexpr size_t SZ_HOUT  = (size_t)TT*512*2;
constexpr size_t OFF_FE   = OFF_HOUT + SZ_HOUT;             // f32 [T][20]
constexpr size_t SZ_FE    = (size_t)TT*LL*4;
constexpr size_t OFF_P    = OFF_FE + SZ_FE;                 // f32 [256][20][20]
constexpr size_t SZ_P     = 256ull*400*4;
constexpr size_t OFF_BAL  = OFF_P + SZ_P;                   // f32 [257][20]
constexpr size_t SZ_BAL   = 20736;
constexpr size_t OFF_BP   = OFF_BAL + SZ_BAL;               // u8 [T][20]
constexpr size_t SZ_BP    = (size_t)TT*LL;
constexpr size_t OFF_M    = OFF_BP + SZ_BP;                 // u8 [256][20]
constexpr size_t SZ_M     = 256ull*LL;
constexpr size_t OFF_EG   = OFF_M + SZ_M + 64;              // i32 [256]

// ---------- prep kernels ----------

__global__ void k_gather(const int* __restrict__ x, const float* __restrict__ emb,
                         unsigned short* __restrict__ X){
  int t = blockIdx.x;
  int xt = x[t];
  const float4* src = (const float4*)(emb + (size_t)xt * EE);
  float4 v = src[threadIdx.x];
  ushort4 o;
  o.x = f2bf(v.x); o.y = f2bf(v.y); o.z = f2bf(v.z); o.w = f2bf(v.w);
  ((ushort4*)(X + (size_t)t * EE))[threadIdx.x] = o;
}

__global__ void k_wih(const float* __restrict__ wf, const float* __restrict__ wb,
                      unsigned short* __restrict__ WIH){
  int gid = blockIdx.x * 256 + threadIdx.x;   // 65536
  int row = gid >> 5, c8 = gid & 31;
  const float* src = (row < 1024 ? wf + (size_t)row * EE : wb + (size_t)(row - 1024) * EE) + c8 * 8;
  unsigned short* dst = WIH + (size_t)row * 256 + c8 * 8;
#pragma unroll
  for (int i = 0; i < 8; i++) dst[i] = f2bf(src[i]);
}

__global__ void k_bias(const float* bf, const float* hf, const float* bb, const float* hb,
                       float* __restrict__ bias){
  int i = blockIdx.x * 256 + threadIdx.x;     // 2048
  int r = i & 1023;
  bias[i] = (i < 1024) ? (bf[r] + hf[r]) : (bb[r] + hb[r]);
}

// w_out -> bf16, padded to 32 rows
__global__ void k_wout(const float* __restrict__ wout, unsigned short* __restrict__ WOP){
  int gid = blockIdx.x * 256 + threadIdx.x;   // 16384 = 32*512
  int row = gid >> 9, k = gid & 511;
  WOP[gid] = (row < LL) ? f2bf(wout[row * 512 + k]) : 0;
}

// quantize W_hh rows to int8 (per-row scale) into MFMA B-fragment layout.
// Row R = g*256+J, J = w*32 + tp*16 + n. Wave w, n-tile nt = g*2+tp covers rows
// n = 0..15 (cols of C). B-fragment (k_gemm_u convention): lane (q*16+n) holds
// row n's k-slice [kt*64 + q*16 .. +15] as 4 packed u32.
// WQ v4i index: (((d*8 + w)*8 + nt)*4 + kt)*64 + lane.
__global__ void k_whh8(const float* __restrict__ whf, const float* __restrict__ whb,
                       unsigned int* __restrict__ WQ, float* __restrict__ FS){
  int row = blockIdx.x;       // 0..2047
  int d = row >> 10, R = row & 1023;
  int g = R >> 8, J = R & 255;
  int w = J >> 5, tp = (J >> 4) & 1, n = J & 15;
  int nt = g * 2 + tp;
  const float* W = (d ? whb : whf) + (size_t)R * 256;
  int t = threadIdx.x;        // 0..63 ; covers cols 4t..4t+3
  float4 v = ((const float4*)W)[t];
  float m = fmaxf(fmaxf(fabsf(v.x), fabsf(v.y)), fmaxf(fabsf(v.z), fabsf(v.w)));
#pragma unroll
  for (int o = 32; o >= 1; o >>= 1) m = fmaxf(m, __shfl_down(m, o));
  m = __shfl(m, 0);
  float sc = (m > 0.f) ? (m / 127.f) : 1.f;
  float inv = 1.f / sc;
  int a = (int)rintf(v.x * inv), b = (int)rintf(v.y * inv);
  int c = (int)rintf(v.z * inv), e4 = (int)rintf(v.w * inv);
  unsigned int pack = ((unsigned)a & 255u) | (((unsigned)b & 255u) << 8)
                    | (((unsigned)c & 255u) << 16) | (((unsigned)e4 & 255u) << 24);
  int kt = t >> 4, q = (t >> 2) & 3, comp = t & 3;
  int lane = q * 16 + n;
  size_t widx = ((((size_t)d * 8 + w) * 8 + nt) * 4 + kt) * 64 + lane;
  WQ[widx * 4 + comp] = pack;
  if (t == 0) FS[((size_t)d * 256 + J) * 4 + g] = sc;
}

// U[d][t][J][g] = bf16( X[t]·W_ih row (g*256+J) + bias )  via 16x16x32 bf16 MFMA
__global__ void k_gemm_u(const unsigned short* __restrict__ X,
                         const unsigned short* __restrict__ WIH,
                         const float* __restrict__ bias,
                         unsigned short* __restrict__ U){
  int wave = threadIdx.x >> 6, l = threadIdx.x & 63;
  int tile = blockIdx.x * 4 + wave;           // 0..32767
  int mt = tile & 255, nt = tile >> 8;        // 256 x 128 tiles
  int lm = l & 15, lq = l >> 4;
  const unsigned short* Arow = X   + (size_t)(mt * 16 + lm) * 256 + lq * 8;
  const unsigned short* Brow = WIH + (size_t)(nt * 16 + lm) * 256 + lq * 8;
  v4f acc = {0.f, 0.f, 0.f, 0.f};
#pragma unroll
  for (int kb = 0; kb < 8; kb++){
    v8s a = *(const v8s*)(Arow + kb * 32);
    v8s b = *(const v8s*)(Brow + kb * 32);
    acc = __builtin_amdgcn_mfma_f32_16x16x32_bf16(a, b, acc, 0, 0, 0);
  }
  int n = nt * 16 + lm;                       // 0..2047 gate-row
  int dd = n >> 10, r = n & 1023;
  int g = r >> 8, J = r & 255;
  float bi = bias[n];
#pragma unroll
  for (int r4 = 0; r4 < 4; r4++){
    int t = mt * 16 + lq * 4 + r4;
    U[(((size_t)(dd * TT + t)) * 256 + J) * 4 + g] = f2bf(acc[r4] + bi);
  }
}

// ---------- the recurrent core ----------
// grid=2 (one CU per direction), block=512 (8 waves, 2/SIMD).
// The matvec z = W_hh·h is done on the MATRIX pipe: v_mfma_i32_16x16x64_i8,
// 256 MFMA/CU/step (~326 cyc/SIMD) instead of 1024 half-rate v_dot4 VALU
// instructions (1024 cyc/SIMD — the measured invariant floor of R0-R5).
// A-operand: h broadcast into all 16 M-rows — lane (m=l&15, q=l>>4) needs
// h[kt*64 + q*16 .. +15]: one conflict-free broadcast ds_read_b128 per k-tile
// (4/step/wave). B-operand: W rows in k_gemm_u's verified fragment convention,
// pre-permuted by k_whh8 (32 v4i = 128 regs/lane; MFMA reads VGPR or AGPR
// natively — no per-use copies, unlike v_dot4). All 16 C rows equal z, so
// lane (n=l&15, tp=l>>5) owns all 4 gates of element Jsel = w*32+tp*16+n:
// the tail (activations, c, h) is fully lane-local, numerics identical to
// R2/R3 (same i8 integers, same scales). h published by lanes q∈{0,2}.

#define NT8(M) M(0) M(1) M(2) M(3) M(4) M(5) M(6) M(7)

#define DECLWB(nt) v4i wb0_##nt, wb1_##nt, wb2_##nt, wb3_##nt;
#define LOADWB(nt) { wb0_##nt = WQv[base + ((nt)*4 + 0) * 64]; \
                     wb1_##nt = WQv[base + ((nt)*4 + 1) * 64]; \
                     wb2_##nt = WQv[base + ((nt)*4 + 2) * 64]; \
                     wb3_##nt = WQv[base + ((nt)*4 + 3) * 64]; }
#define DECLACC(nt) v4i acc_##nt;
#define MFA(nt) acc_##nt = __builtin_amdgcn_mfma_i32_16x16x64_i8(hA0, wb0_##nt, zero,     0, 0, 0);
#define MFB(nt) acc_##nt = __builtin_amdgcn_mfma_i32_16x16x64_i8(hA1, wb1_##nt, acc_##nt, 0, 0, 0);
#define MFC(nt) acc_##nt = __builtin_amdgcn_mfma_i32_16x16x64_i8(hA2, wb2_##nt, acc_##nt, 0, 0, 0);
#define MFD(nt) acc_##nt = __builtin_amdgcn_mfma_i32_16x16x64_i8(hA3, wb3_##nt, acc_##nt, 0, 0, 0);

__global__ void __launch_bounds__(512)
__attribute__((amdgpu_waves_per_eu(2, 2)))
k_lstm12(
    const unsigned short* __restrict__ U, const v4i* __restrict__ WQv,
    const float4* __restrict__ FS4, const float* __restrict__ h0,
    const float* __restrict__ c0, unsigned short* __restrict__ hout){
  int d = blockIdx.x;
  int tid = threadIdx.x;        // 0..511
  int w = tid >> 6;
  int l = tid & 63;
  int q = l >> 4;               // K-slice group / C-row group
  int n = l & 15;               // C column = W row within n-tile
  int tp = l >> 5;              // element half selector
  int Jsel = w * 32 + tp * 16 + n;   // this lane's hidden element
  bool pub = ((l & 16) == 0);   // q==0 publishes tp=0 elems, q==2 publishes tp=1

  __shared__ __align__(16) unsigned char hb[2][256];

  NT8(DECLWB)
  {
    size_t base = ((size_t)(d * 8 + w)) * 2048 + l;   // v4i units
    NT8(LOADWB)
  }

  float4 fsv = FS4[(size_t)d * 256 + Jsel];
  float fs8x = fsv.x * (8.f/127.f), fs1x = fsv.x * (1.f/127.f);
  float fs8y = fsv.y * (8.f/127.f), fs1y = fsv.y * (1.f/127.f);
  float fs8z = fsv.z * (8.f/127.f), fs1z = fsv.z * (1.f/127.f);
  float fs8w = fsv.w * (8.f/127.f), fs1w = fsv.w * (1.f/127.f);

  float cst = c0[d * 256 + Jsel];
  if (pub){
    float hini = h0[d * 256 + Jsel];
    hini = fminf(fmaxf(hini, -8.f), 8.f);
    hb[0][Jsel] = (unsigned char)(char)(int)rintf(hini * (127.f / 8.f));
  }

  const unsigned short* Up0 = U + (size_t)d * TT * 1024 + (size_t)Jsel * 4;
  int stp = d ? -1 : 1;
  int tA = d ? TT - 1 : 0;
  uint2 u_c = *(const uint2*)(Up0 + (size_t)tA * 1024);
  uint2 u_n = *(const uint2*)(Up0 + (size_t)(tA + stp) * 1024);

  unsigned short* hp = hout + (size_t)tA * 512 + d * 256 + Jsel;

  v4i zero = {0, 0, 0, 0};

  __syncthreads();

  for (int s = 0; s < TT; s++){
    int par = s & 1;
    int tt = d ? (TT - 1 - s) : s;

    // A fragments: h broadcast — lane (m,q) reads h[kt*64 + q*16 .. +15]
    const char* hbase = (const char*)(&hb[par][0]) + (q << 4);
    v4i hA0 = *(const v4i*)(hbase);
    v4i hA1 = *(const v4i*)(hbase + 64);
    v4i hA2 = *(const v4i*)(hbase + 128);
    v4i hA3 = *(const v4i*)(hbase + 192);

    NT8(DECLACC)
    NT8(MFA)        // kt=0 (C=0)
    NT8(MFB)        // kt=1
    NT8(MFC)        // kt=2
    NT8(MFD)        // kt=3

    // all 16 C rows equal z[n]; pick this lane's element (tp) per gate
    int aI = tp ? acc_1[0] : acc_0[0];
    int aF = tp ? acc_3[0] : acc_2[0];
    int aG = tp ? acc_5[0] : acc_4[0];
    int aO = tp ? acc_7[0] : acc_6[0];

    bool s0 = (s == 0);
    float fx = s0 ? fs8x : fs1x;
    float fy = s0 ? fs8y : fs1y;
    float fz = s0 ? fs8z : fs1z;
    float fw = s0 ? fs8w : fs1w;

    float u_i = bf2f((unsigned short)(u_c.x & 0xffffu));
    float u_f = bf2f((unsigned short)(u_c.x >> 16));
    float u_g = bf2f((unsigned short)(u_c.y & 0xffffu));
    float u_o = bf2f((unsigned short)(u_c.y >> 16));
    float zi = fmaf((float)aI, fx, u_i);
    float zf = fmaf((float)aF, fy, u_f);
    float zg = fmaf((float)aG, fz, u_g);
    float zo = fmaf((float)aO, fw, u_o);

    // rotate u prefetch (2 steps ahead; clamped always-load)
    u_c = u_n;
    {
      int t2 = tt + 2 * stp;
      t2 = t2 < 0 ? 0 : (t2 > TT - 1 ? TT - 1 : t2);
      u_n = *(const uint2*)(Up0 + (size_t)t2 * 1024);
    }

    // activations (lane-local, all 4 gates)
    float za = fminf(fmaxf(zi, -87.f), 87.f);
    float ea = __expf(-za);
    float gi = __builtin_amdgcn_rcpf(1.f + ea);
    float zb = fminf(fmaxf(zf, -87.f), 87.f);
    float eb = __expf(-zb);
    float gf = __builtin_amdgcn_rcpf(1.f + eb);
    float zc = fminf(fmaxf(zg, -20.f), 20.f);
    float ec = __expf(-2.f * zc);
    float gg = (1.f - ec) * __builtin_amdgcn_rcpf(1.f + ec);
    float zd = fminf(fmaxf(zo, -87.f), 87.f);
    float ed = __expf(-zd);
    float go = __builtin_amdgcn_rcpf(1.f + ed);

    cst = fmaf(gf, cst, gi * gg);
    float cc = fminf(fmaxf(cst, -20.f), 20.f);
    float e2 = __expf(-2.f * cc);
    float th = (1.f - e2) * __builtin_amdgcn_rcpf(1.f + e2);
    float h = go * th;

    if (pub){
      int qv = (int)rintf(fminf(fmaxf(h, -1.f), 1.f) * 127.f);
      hb[par ^ 1][Jsel] = (unsigned char)(char)qv;
      *hp = f2bf(h);
    }
    hp += stp * 512;

    BARRIER_LDS();
  }
}

// feats via MFMA: FE[t][j] = HOUT[t]·WOP[j] + bout[j], WOP padded to 32 rows
__global__ void k_feats2(const unsigned short* __restrict__ HOUT,
                         const unsigned short* __restrict__ WOP,
                         const float* __restrict__ bout,
                         float* __restrict__ feats){
  int wave = threadIdx.x >> 6, l = threadIdx.x & 63;
  int tile = blockIdx.x * 4 + wave;           // 0..511
  int mt = tile & 255, nt = tile >> 8;        // 256 M-tiles x 2 N-tiles
  int lm = l & 15, lq = l >> 4;
  const unsigned short* Arow = HOUT + (size_t)(mt * 16 + lm) * 512 + lq * 8;
  const unsigned short* Brow = WOP  + (size_t)(nt * 16 + lm) * 512 + lq * 8;
  v4f acc = {0.f, 0.f, 0.f, 0.f};
#pragma unroll
  for (int kb = 0; kb < 16; kb++){
    v8s a = *(const v8s*)(Arow + kb * 32);
    v8s b = *(const v8s*)(Brow + kb * 32);
    acc = __builtin_amdgcn_mfma_f32_16x16x32_bf16(a, b, acc, 0, 0, 0);
  }
  int n = nt * 16 + lm;
  if (n < LL){
    float bi = bout[n];
#pragma unroll
    for (int r4 = 0; r4 < 4; r4++){
      int t = mt * 16 + lq * 4 + r4;
      feats[t * LL + n] = acc[r4] + bi;
    }
  }
}

// V1: per-chunk max-plus matrix product
__global__ void k_vchunk(const float* __restrict__ feats, const float* __restrict__ trans,
                         float* __restrict__ P){
  int c = blockIdx.x, j = threadIdx.x;
  __shared__ float Ps[2][LL][LL];
  bool act = j < LL;
  float trow[LL];
  if (act){
#pragma unroll
    for (int i = 0; i < LL; i++) trow[i] = trans[j * LL + i];
    for (int i = 0; i < LL; i++) Ps[0][i][j] = (i == j) ? 0.f : -1e30f;
  }
  __syncthreads();
  for (int s = 0; s < 16; s++){
    int t = c * 16 + s;
    int pb = s & 1;
    if (act){
      float fj = feats[t * LL + j];
      for (int i = 0; i < LL; i++){
        float m = Ps[pb][i][0] + trow[0];
#pragma unroll
        for (int mm = 1; mm < LL; mm++) m = fmaxf(m, Ps[pb][i][mm] + trow[mm]);
        Ps[pb ^ 1][i][j] = m + fj;
      }
    }
    __syncthreads();
  }
  if (act)
    for (int i = 0; i < LL; i++) P[((size_t)c * LL + i) * LL + j] = Ps[0][i][j];
}

// V2: sequential boundary-alpha scan (prefetch-pipelined)
__global__ void k_vscan(const float* __restrict__ P, float* __restrict__ bal){
  int tid = threadIdx.x;
  bool act = tid < LL;
  __shared__ float al[LL];
  __shared__ float Pl[400];
  if (act){
    float a = (tid == STARTT) ? 0.f : NEGV;
    al[tid] = a;
    bal[tid] = a;
  }
  for (int k = tid; k < 400; k += 64) Pl[k] = P[k];
  __syncthreads();
  for (int c = 0; c < NCH; c++){
    float p0 = 0.f, p1 = 0.f, p2 = 0.f, p3 = 0.f, p4 = 0.f, p5 = 0.f, p6 = 0.f;
    if (c + 1 < NCH){
      const float* Pn = P + (size_t)(c + 1) * 400;
      p0 = Pn[tid];        p1 = Pn[tid + 64];  p2 = Pn[tid + 128];
      p3 = Pn[tid + 192];  p4 = Pn[tid + 256]; p5 = Pn[tid + 320];
      if (tid + 384 < 400) p6 = Pn[tid + 384];
    }
    float m = -1e30f;
    if (act){
      m = al[0] + Pl[tid];
#pragma unroll
      for (int i = 1; i < LL; i++) m = fmaxf(m, al[i] + Pl[i * LL + tid]);
    }
    __syncthreads();
    if (act){
      al[tid] = m;
      bal[(c + 1) * LL + tid] = m;
    }
    if (c + 1 < NCH){
      Pl[tid] = p0;        Pl[tid + 64] = p1;  Pl[tid + 128] = p2;
      Pl[tid + 192] = p3;  Pl[tid + 256] = p4; Pl[tid + 320] = p5;
      if (tid + 384 < 400) Pl[tid + 384] = p6;
    }
    __syncthreads();
  }
}

// V3: per-chunk backpointers + chunk backtrace map
__global__ void k_vbp(const float* __restrict__ feats, const float* __restrict__ trans,
                      const float* __restrict__ bal, unsigned char* __restrict__ bp,
                      unsigned char* __restrict__ M){
  int c = blockIdx.x, j = threadIdx.x;
  bool act = j < LL;
  __shared__ float al[2][LL];
  __shared__ unsigned char bpl[16][LL];
  float trow[LL];
  if (act){
#pragma unroll
    for (int i = 0; i < LL; i++) trow[i] = trans[j * LL + i];
    al[0][j] = bal[c * LL + j];
  }
  __syncthreads();
  for (int s = 0; s < 16; s++){
    int t = c * 16 + s;
    int pb = s & 1;
    if (act){
      float m = al[pb][0] + trow[0];
      int arg = 0;
#pragma unroll
      for (int i = 1; i < LL; i++){
        float v = al[pb][i] + trow[i];
        if (v > m){ m = v; arg = i; }
      }
      bpl[s][j] = (unsigned char)arg;
      bp[(size_t)t * LL + j] = (unsigned char)arg;
      al[pb ^ 1][j] = m + feats[t * LL + j];
    }
    __syncthreads();
  }
  if (act){
    int tag = j;
    for (int s = 15; s >= 0; s--) tag = bpl[s][tag];
    M[c * LL + j] = (unsigned char)tag;
  }
}

// V4: final score + chunk-boundary tag chase
__global__ void k_vtag(const float* __restrict__ bal, const float* __restrict__ trans,
                       const unsigned char* __restrict__ M, int* __restrict__ Eg,
                       float* __restrict__ out){
  int tid = threadIdx.x;
  __shared__ unsigned char Ml[NCH * LL];
  __shared__ float fin[LL];
  for (int k = tid; k < NCH * LL; k += 64) Ml[k] = M[k];
  if (tid < LL) fin[tid] = bal[NCH * LL + tid] + trans[STOPP * LL + tid];
  __syncthreads();
  if (tid == 0){
    float m = fin[0]; int arg = 0;
    for (int i = 1; i < LL; i++) if (fin[i] > m){ m = fin[i]; arg = i; }
    out[0] = m;
    int tag = arg;
    Eg[NCH - 1] = tag;
    for (int c = NCH - 1; c >= 1; c--){
      tag = Ml[c * LL + tag];
      Eg[c - 1] = tag;
    }
  }
}

// V5: parallel path emission
__global__ void k_vemit(const int* __restrict__ Eg, const unsigned char* __restrict__ bp,
                        float* __restrict__ out){
  int c = threadIdx.x;
  int tag = Eg[c];
  out[1 + c * 16 + 15] = (float)tag;
  for (int s = 15; s >= 1; s--){
    tag = bp[(size_t)(c * 16 + s) * LL + tag];
    out[1 + c * 16 + s - 1] = (float)tag;
  }
}

// ---------- launcher ----------
extern "C" void kernel_launch(void* const* d_in, const int* in_sizes, int n_in,
                              void* d_out, int out_size, void* d_ws, size_t ws_size,
                              hipStream_t stream){
  (void)in_sizes; (void)n_in; (void)out_size; (void)ws_size;
  const int*   x     = (const int*)d_in[0];
  const float* emb   = (const float*)d_in[1];
  const float* wihf  = (const float*)d_in[2];
  const float* whhf  = (const float*)d_in[3];
  const float* bihf  = (const float*)d_in[4];
  const float* bhhf  = (const float*)d_in[5];
  const float* wihb  = (const float*)d_in[6];
  const float* whhb  = (const float*)d_in[7];
  const float* bihb  = (const float*)d_in[8];
  const float* bhhb  = (const float*)d_in[9];
  const float* wout  = (const float*)d_in[10];
  const float* bout  = (const float*)d_in[11];
  const float* trans = (const float*)d_in[12];
  const float* h0    = (const float*)d_in[13];
  const float* c0    = (const float*)d_in[14];
  float* out = (float*)d_out;
  char* ws = (char*)d_ws;

  unsigned short* U    = (unsigned short*)(ws + OFF_U);
  unsigned short* X    = (unsigned short*)(ws + OFF_X);
  unsigned short* WIH  = (unsigned short*)(ws + OFF_WIH);
  float*          BIAS = (float*)(ws + OFF_BIAS);
  unsigned int*   WQ   = (unsigned int*)(ws + OFF_WQ);
  float*          FS   = (float*)(ws + OFF_FS);
  unsigned short* WOP  = (unsigned short*)(ws + OFF_WOP);
  unsigned short* HOUT = (unsigned short*)(ws + OFF_HOUT);
  float*          FE   = (float*)(ws + OFF_FE);
  float*          P    = (float*)(ws + OFF_P);
  float*          BAL  = (float*)(ws + OFF_BAL);
  unsigned char*  BP   = (unsigned char*)(ws + OFF_BP);
  unsigned char*  M    = (unsigned char*)(ws + OFF_M);
  int*            EG   = (int*)(ws + OFF_EG);

  k_gather<<<TT, 64, 0, stream>>>(x, emb, X);
  k_wih<<<256, 256, 0, stream>>>(wihf, wihb, WIH);
  k_bias<<<8, 256, 0, stream>>>(bihf, bhhf, bihb, bhhb, BIAS);
  k_wout<<<64, 256, 0, stream>>>(wout, WOP);
  k_whh8<<<2048, 64, 0, stream>>>(whhf, whhb, WQ, FS);
  k_gemm_u<<<8192, 256, 0, stream>>>(X, WIH, BIAS, U);
  k_lstm12<<<2, 512, 0, stream>>>(U, (const v4i*)WQ, (const float4*)FS, h0, c0, HOUT);
  k_feats2<<<128, 256, 0, stream>>>(HOUT, WOP, bout, FE);
  k_vchunk<<<NCH, 64, 0, stream>>>(FE, trans, P);
  k_vscan<<<1, 64, 0, stream>>>(P, BAL);
  k_vbp<<<NCH, 64, 0, stream>>>(FE, trans, BAL, BP, M);
  k_vtag<<<1, 64, 0, stream>>>(BAL, trans, M, EG, out);
  k_vemit<<<1, 256, 0, stream>>>(EG, BP, out);
}